// Round 9
// baseline (118.374 us; speedup 1.0000x reference)
//
#include <hip/hip_runtime.h>

#define NQ 32768
#define NC 8192
#define CFEAT 128
#define CSPLIT 64
#define TILE (NC / CSPLIT)   // 128 coords per split
#define BLK 256
#define QPT 8                // queries per thread
#define QPB (BLK * QPT)      // 2048 queries per block

// ws layout: [0, 8 MB) f32 bestd[CSPLIT][NQ] (phase-1 stores AND phase-2
// reads both lane-coalesced); then float4 ctab[NC] (128 KB).
#define BESTD_OFF 0
#define CTAB_OFF ((size_t)CSPLIT * NQ * 4)

// Precompute coord table (-2cx,-2cy,-2cz,cc) once.
// cc rounding order matches np.sum(coords*coords, -1): ((x*x+y*y)+z*z).
__global__ __launch_bounds__(256) void init_ctab(
    const float* __restrict__ coords, float4* __restrict__ ctab) {
  const int t = blockIdx.x * 256 + threadIdx.x;   // grid covers NC threads
  const float cx = coords[t * 3 + 0];
  const float cy = coords[t * 3 + 1];
  const float cz = coords[t * 3 + 2];
  const float cc = __fadd_rn(
      __fadd_rn(__fmul_rn(cx, cx), __fmul_rn(cy, cy)), __fmul_rn(cz, cz));
  ctab[t] = make_float4(-2.0f * cx, -2.0f * cy, -2.0f * cz, cc);
}

// Phase 1: per-split min DISTANCE only. 2 coords per iteration + v_min3
// (fminf(fminf(best,da),db)) = 9 VALU / 2 pairs = 4.5/pair -> 15.4 us floor.
// QPT=8: one wave-uniform s_load batch feeds 8 query chains (halves stall
// share per VALU vs QPT=4). grid (16,64) = 4096 waves = 16/CU at
// __launch_bounds__(256,4) (128-VGPR cap, no spill).
//
// Numerics (BIT-EXACT vs harness reference, verified absmax=0.0):
//   t = (-2cx)*px; t = fma(-2cy,py,t); t = fma(-2cz,pz,t); d = cc + t
// (-2 pre-fold is a power-of-2 scale: exact, commutes with round-to-nearest.)
// min/min3 are value-exact and order-independent on finite inputs.
__global__ __launch_bounds__(BLK, 4) void argmin_split(
    const float4* __restrict__ ctab, const float* __restrict__ points,
    float* __restrict__ bestd) {
  const int s = blockIdx.y;
  const int base = s * TILE;
  const int q0 = blockIdx.x * QPB + threadIdx.x;

  float px[QPT], py[QPT], pz[QPT], best[QPT];
  #pragma unroll
  for (int k = 0; k < QPT; ++k) {
    const int q = q0 + k * BLK;
    px[k] = points[q * 3 + 0];
    py[k] = points[q * 3 + 1];
    pz[k] = points[q * 3 + 2];
    best[k] = __builtin_inff();
  }

  #pragma unroll 2
  for (int i = 0; i < TILE; i += 2) {
    const float4 ca = ctab[base + i];       // wave-uniform -> s_load
    const float4 cb = ctab[base + i + 1];
    #pragma unroll
    for (int k = 0; k < QPT; ++k) {
      float ta = __fmul_rn(ca.x, px[k]);
      ta = __fmaf_rn(ca.y, py[k], ta);
      ta = __fmaf_rn(ca.z, pz[k], ta);
      const float da = __fadd_rn(ca.w, ta);
      float tb = __fmul_rn(cb.x, px[k]);
      tb = __fmaf_rn(cb.y, py[k], tb);
      tb = __fmaf_rn(cb.z, pz[k], tb);
      const float db = __fadd_rn(cb.w, tb);
      best[k] = fminf(fminf(best[k], da), db);   // v_min3_f32
    }
  }

  #pragma unroll
  for (int k = 0; k < QPT; ++k) {
    const int q = q0 + k * BLK;
    bestd[(size_t)s * NQ + q] = best[k];    // lane-coalesced 256 B/wave
  }
}

// Phase 2 (one 64-thread wave per 64 queries, lane = query): reduce the 64
// split-mins with COALESCED reads (lanes are consecutive q), tracking the
// first split attaining the min (strict <, ascending s). Then each lane
// rescans its winning split's 128 coords (bit-exact recompute guarantees an
// equality hit; first i with d==m = lowest index within split). Tiebreak
// chain == np.argmin global first-index. Finally a shfl-redistributed,
// fully-coalesced feature gather (half-wave per row, float4).
__global__ __launch_bounds__(64) void reduce_rescan_gather(
    const float4* __restrict__ ctab, const float* __restrict__ points,
    const float* __restrict__ bestd, const float* __restrict__ feature,
    float4* __restrict__ out) {
  const int l = threadIdx.x;            // 0..63
  const int qbase = blockIdx.x * 64;
  const int q = qbase + l;

  // 1) reduce over splits; bestd[s][q] reads are lane-coalesced (256 B/inst)
  float m = __builtin_inff();
  int sb = 0;
  #pragma unroll 8
  for (int s = 0; s < CSPLIT; ++s) {
    const float v = bestd[(size_t)s * NQ + q];
    const bool lt = v < m;              // strict <: first split wins ties
    m = lt ? v : m;
    sb = lt ? s : sb;
  }

  // 2) divergent per-lane rescan of split sb (ctab is 128 KB, L2-resident)
  const float px = points[q * 3 + 0];
  const float py = points[q * 3 + 1];
  const float pz = points[q * 3 + 2];
  const int base = sb * TILE;
  int ii = TILE;
  #pragma unroll 8
  for (int i = 0; i < TILE; ++i) {
    const float4 c = ctab[base + i];
    float t = __fmul_rn(c.x, px);
    t = __fmaf_rn(c.y, py, t);
    t = __fmaf_rn(c.z, pz, t);
    const float d = __fadd_rn(c.w, t);
    ii = (d == m) ? min(ii, i) : ii;    // keeps first match (ascending i)
  }
  const int idx = base + ii;

  // 3) coalesced gather: pass p writes rows 2p (lanes 0-31) and 2p+1 (32-63)
  for (int p = 0; p < 32; ++p) {
    const int r = 2 * p + (l >> 5);
    const int j = l & 31;
    const int ridx = __shfl(idx, r, 64);     // query (qbase+r)'s coord index
    out[((size_t)qbase + r) * (CFEAT / 4) + j] =
        ((const float4*)feature)[(size_t)ridx * (CFEAT / 4) + j];
  }
}

extern "C" void kernel_launch(void* const* d_in, const int* in_sizes, int n_in,
                              void* d_out, int out_size, void* d_ws, size_t ws_size,
                              hipStream_t stream) {
  const float* coords  = (const float*)d_in[0];   // [8192, 3]
  const float* feature = (const float*)d_in[1];   // [8192, 128]
  const float* points  = (const float*)d_in[2];   // [32768, 3]
  float* out = (float*)d_out;                     // [32768, 128]

  float* bestd = (float*)((char*)d_ws + BESTD_OFF);
  float4* ctab = (float4*)((char*)d_ws + CTAB_OFF);

  init_ctab<<<NC / 256, 256, 0, stream>>>(coords, ctab);

  dim3 grid1(NQ / QPB, CSPLIT);                   // (16, 64) = 1024 blocks
  argmin_split<<<grid1, BLK, 0, stream>>>(ctab, points, bestd);

  reduce_rescan_gather<<<NQ / 64, 64, 0, stream>>>(ctab, points, bestd,
                                                   feature, (float4*)out);
}

// Round 10
// 117.199 us; speedup vs baseline: 1.0100x; 1.0100x over previous
//
#include <hip/hip_runtime.h>

#define NQ 32768
#define NC 8192
#define CFEAT 128
#define CSPLIT 128
#define TILE (NC / CSPLIT)   // 64 coords per split
#define BLK 256
#define QPT 8                // queries per thread
#define QPB (BLK * QPT)      // 2048 queries per block

// ws layout: bestd[CSPLIT][NQ] f32 (16 MB, both phases coalesced);
// outm[NQ] f32; outs[NQ] i32; ctab[NC] float4.
#define BESTD_OFF 0
#define OUTM_OFF ((size_t)CSPLIT * NQ * 4)
#define OUTS_OFF (OUTM_OFF + (size_t)NQ * 4)
#define CTAB_OFF (OUTS_OFF + (size_t)NQ * 4)

// Precompute coord table (-2cx,-2cy,-2cz,cc) once.
// cc rounding order matches np.sum(coords*coords, -1): ((x*x+y*y)+z*z).
__global__ __launch_bounds__(256) void init_ctab(
    const float* __restrict__ coords, float4* __restrict__ ctab) {
  const int t = blockIdx.x * 256 + threadIdx.x;   // grid covers NC threads
  const float cx = coords[t * 3 + 0];
  const float cy = coords[t * 3 + 1];
  const float cz = coords[t * 3 + 2];
  const float cc = __fadd_rn(
      __fadd_rn(__fmul_rn(cx, cx), __fmul_rn(cy, cy)), __fmul_rn(cz, cz));
  ctab[t] = make_float4(-2.0f * cx, -2.0f * cy, -2.0f * cz, cc);
}

// Phase 1: per-split min DISTANCE only. 2 coords/iter + v_min3 = 4.5
// VALU/pair. CSPLIT=128 -> 2048 blocks = 32 waves/CU cap (R9 was 16/CU,
// avg occupancy 25% — raising the cap is this round's phase-1 lever).
//
// Numerics (BIT-EXACT vs harness reference, verified absmax=0.0):
//   t = (-2cx)*px; t = fma(-2cy,py,t); t = fma(-2cz,pz,t); d = cc + t
// (-2 pre-fold is a power-of-2 scale: exact, commutes with round-to-nearest.)
// min/min3 value is order-independent on finite inputs.
__global__ __launch_bounds__(BLK, 8) void argmin_split(
    const float4* __restrict__ ctab, const float* __restrict__ points,
    float* __restrict__ bestd) {
  const int s = blockIdx.y;
  const int base = s * TILE;
  const int q0 = blockIdx.x * QPB + threadIdx.x;

  float px[QPT], py[QPT], pz[QPT], best[QPT];
  #pragma unroll
  for (int k = 0; k < QPT; ++k) {
    const int q = q0 + k * BLK;
    px[k] = points[q * 3 + 0];
    py[k] = points[q * 3 + 1];
    pz[k] = points[q * 3 + 2];
    best[k] = __builtin_inff();
  }

  #pragma unroll 2
  for (int i = 0; i < TILE; i += 2) {
    const float4 ca = ctab[base + i];       // wave-uniform address
    const float4 cb = ctab[base + i + 1];
    #pragma unroll
    for (int k = 0; k < QPT; ++k) {
      float ta = __fmul_rn(ca.x, px[k]);
      ta = __fmaf_rn(ca.y, py[k], ta);
      ta = __fmaf_rn(ca.z, pz[k], ta);
      const float da = __fadd_rn(ca.w, ta);
      float tb = __fmul_rn(cb.x, px[k]);
      tb = __fmaf_rn(cb.y, py[k], tb);
      tb = __fmaf_rn(cb.z, pz[k], tb);
      const float db = __fadd_rn(cb.w, tb);
      best[k] = fminf(fminf(best[k], da), db);   // v_min3_f32
    }
  }

  #pragma unroll
  for (int k = 0; k < QPT; ++k) {
    const int q = q0 + k * BLK;
    bestd[(size_t)s * NQ + q] = best[k];    // lane-coalesced 256 B/wave
  }
}

// Phase 2a: per-query reduce over the 128 split-mins. Lane = query ->
// bestd[s][q] reads are fully coalesced. Strict < over ascending s keeps
// the lowest split attaining the min (= globally-first index range).
__global__ __launch_bounds__(256) void reduce_splits(
    const float* __restrict__ bestd, float* __restrict__ outm,
    int* __restrict__ outs) {
  const int q = blockIdx.x * 256 + threadIdx.x;
  float m = __builtin_inff();
  int sb = 0;
  #pragma unroll 8
  for (int s = 0; s < CSPLIT; ++s) {
    const float v = bestd[(size_t)s * NQ + q];
    const bool lt = v < m;               // strict <: first split wins ties
    m = lt ? v : m;
    sb = lt ? s : sb;
  }
  outm[q] = m;
  outs[q] = sb;
}

// Phase 2b: one wave per query (32768 waves — the R7-proven parallel shape).
// Lane l evaluates coord (sb*64+l) of the winning split: bit-exact recompute
// guarantees an equality hit; ballot+ffs -> lowest lane = lowest index within
// the split. Tiebreak chain == np.argmin global first-index. Then a coalesced
// float2 feature-row gather (64 lanes x 8 B = 512 B).
__global__ __launch_bounds__(256) void rescan_gather(
    const float4* __restrict__ ctab, const float* __restrict__ points,
    const float* __restrict__ outm, const int* __restrict__ outs,
    const float* __restrict__ feature, float2* __restrict__ out) {
  const int q = blockIdx.x * 4 + (threadIdx.x >> 6);
  const int l = threadIdx.x & 63;

  const float m = outm[q];              // wave-uniform broadcast loads
  const int sb = outs[q];
  const int base = sb * TILE;           // TILE == 64: one coord per lane

  const float px = points[q * 3 + 0];
  const float py = points[q * 3 + 1];
  const float pz = points[q * 3 + 2];

  const float4 c = ctab[base + l];      // coalesced, lanes consecutive
  float t = __fmul_rn(c.x, px);
  t = __fmaf_rn(c.y, py, t);
  t = __fmaf_rn(c.z, pz, t);
  const float d = __fadd_rn(c.w, t);

  const unsigned long long b = __ballot(d == m);
  const int idx = base + __ffsll(b) - 1;

  out[(size_t)q * (CFEAT / 2) + l] =
      ((const float2*)feature)[(size_t)idx * (CFEAT / 2) + l];
}

extern "C" void kernel_launch(void* const* d_in, const int* in_sizes, int n_in,
                              void* d_out, int out_size, void* d_ws, size_t ws_size,
                              hipStream_t stream) {
  const float* coords  = (const float*)d_in[0];   // [8192, 3]
  const float* feature = (const float*)d_in[1];   // [8192, 128]
  const float* points  = (const float*)d_in[2];   // [32768, 3]
  float* out = (float*)d_out;                     // [32768, 128]

  float* bestd = (float*)((char*)d_ws + BESTD_OFF);
  float* outm  = (float*)((char*)d_ws + OUTM_OFF);
  int*   outs  = (int*)((char*)d_ws + OUTS_OFF);
  float4* ctab = (float4*)((char*)d_ws + CTAB_OFF);

  init_ctab<<<NC / 256, 256, 0, stream>>>(coords, ctab);

  dim3 grid1(NQ / QPB, CSPLIT);                   // (16, 128) = 2048 blocks
  argmin_split<<<grid1, BLK, 0, stream>>>(ctab, points, bestd);

  reduce_splits<<<NQ / 256, 256, 0, stream>>>(bestd, outm, outs);

  rescan_gather<<<NQ / 4, 256, 0, stream>>>(ctab, points, outm, outs,
                                            feature, (float2*)out);
}